// Round 12
// baseline (111.916 us; speedup 1.0000x reference)
//
#include <hip/hip_runtime.h>
#include <hip/hip_bf16.h>

// B=4, S=2048, D=1024, H=16, DH=64
typedef __attribute__((ext_vector_type(4))) float f32x4;
typedef __attribute__((ext_vector_type(8))) short bf16x8;
typedef __attribute__((ext_vector_type(4))) unsigned short u16x4;
typedef __attribute__((ext_vector_type(4))) unsigned int u32x4;

#define MFMA16(a, b, c) __builtin_amdgcn_mfma_f32_16x16x32_bf16((a), (b), (c), 0, 0, 0)

static __device__ __forceinline__ unsigned short f2bf(float f) {
    unsigned u = __float_as_uint(f);
    u += 0x7FFFu + ((u >> 16) & 1u);   // RNE
    return (unsigned short)(u >> 16);
}
// pack 4 floats -> 4 bf16 (round-half-up) as uint2, via v_perm_b32
static __device__ __forceinline__ uint2 pack4_rhu(float4 v) {
    unsigned a = __float_as_uint(v.x) + 0x8000u;
    unsigned b = __float_as_uint(v.y) + 0x8000u;
    unsigned c = __float_as_uint(v.z) + 0x8000u;
    unsigned d = __float_as_uint(v.w) + 0x8000u;
    uint2 r;
    r.x = __builtin_amdgcn_perm(b, a, 0x07060302u);
    r.y = __builtin_amdgcn_perm(d, c, 0x07060302u);
    return r;
}
static __device__ __forceinline__ float exp2_fast(float x) {
#if __has_builtin(__builtin_amdgcn_exp2f)
    return __builtin_amdgcn_exp2f(x);
#else
    return exp2f(x);
#endif
}

// vdst.hi32 <-> vsrc.lo32
static __device__ __forceinline__ void permswap32(unsigned &a, unsigned &b) {
#if __has_builtin(__builtin_amdgcn_permlane32_swap)
    typedef __attribute__((ext_vector_type(2))) unsigned u32x2_t;
    u32x2_t r = __builtin_amdgcn_permlane32_swap(a, b, false, false);
    a = r[0]; b = r[1];
#else
    asm volatile("v_permlane32_swap_b32 %0, %1" : "+v"(a), "+v"(b));
#endif
}
// vdst.row1 <-> vsrc.row0, vdst.row3 <-> vsrc.row2  (row = 16 lanes)
static __device__ __forceinline__ void permswap16(unsigned &a, unsigned &b) {
#if __has_builtin(__builtin_amdgcn_permlane16_swap)
    typedef __attribute__((ext_vector_type(2))) unsigned u32x2_t;
    u32x2_t r = __builtin_amdgcn_permlane16_swap(a, b, false, false);
    a = r[0]; b = r[1];
#else
    asm volatile("v_permlane16_swap_b32 %0, %1" : "+v"(a), "+v"(b));
#endif
}

// scores premultiplied so softmax runs in exp2 domain: c = log2(e)/32
#define QSCALE 0.04508422002778011f

// ---------------- Q projection: q = (x @ Wq^T) * QSCALE, bf16 [B,H,S,DH] ----------------
__global__ __launch_bounds__(256) void qproj_kernel(const float* __restrict__ x,
                                                    const float* __restrict__ wq,
                                                    unsigned short* __restrict__ qout) {
    __shared__ __align__(16) unsigned short As[2][128][40];
    __shared__ __align__(16) unsigned short Bs[2][128][40];
    const int m0 = blockIdx.x * 128;
    const int n0 = blockIdx.y * 128;
    const int tid = threadIdx.x;
    const int wave = tid >> 6, lane = tid & 63;
    const int lg = lane >> 4, lc = lane & 15;
    const int wm = wave >> 1, wn = wave & 1;

    f32x4 acc[4][4];
#pragma unroll
    for (int i = 0; i < 4; ++i)
#pragma unroll
        for (int j = 0; j < 4; ++j) acc[i][j] = (f32x4){0.f, 0.f, 0.f, 0.f};

    float4 ax[4], bx[4];
#pragma unroll
    for (int i = 0; i < 4; ++i) {
        int c = tid + i * 256;
        int row = c >> 3, kc = (c & 7) * 4;
        ax[i] = *(const float4*)(x  + (size_t)(m0 + row) * 1024 + kc);
        bx[i] = *(const float4*)(wq + (size_t)(n0 + row) * 1024 + kc);
    }
#pragma unroll
    for (int i = 0; i < 4; ++i) {
        int c = tid + i * 256;
        int row = c >> 3, kc = (c & 7) * 4;
        *(uint2*)&As[0][row][kc] = pack4_rhu(ax[i]);
        *(uint2*)&Bs[0][row][kc] = pack4_rhu(bx[i]);
    }

    int cur = 0;
    for (int ki = 0; ki < 32; ++ki) {
        __syncthreads();
        const bool havenext = (ki + 1 < 32);
        if (havenext) {
            int ks = (ki + 1) * 32;
#pragma unroll
            for (int i = 0; i < 4; ++i) {
                int c = tid + i * 256;
                int row = c >> 3, kc = (c & 7) * 4;
                ax[i] = *(const float4*)(x  + (size_t)(m0 + row) * 1024 + ks + kc);
                bx[i] = *(const float4*)(wq + (size_t)(n0 + row) * 1024 + ks + kc);
            }
        }
        bf16x8 af[4], bfr[4];
#pragma unroll
        for (int i = 0; i < 4; ++i) {
            af[i]  = *(const bf16x8*)&As[cur][wm * 64 + i * 16 + lc][lg * 8];
            bfr[i] = *(const bf16x8*)&Bs[cur][wn * 64 + i * 16 + lc][lg * 8];
        }
        __builtin_amdgcn_s_setprio(1);
#pragma unroll
        for (int mi = 0; mi < 4; ++mi)
#pragma unroll
            for (int ni = 0; ni < 4; ++ni)
                acc[mi][ni] = MFMA16(af[mi], bfr[ni], acc[mi][ni]);
        __builtin_amdgcn_s_setprio(0);
        if (havenext) {
#pragma unroll
            for (int i = 0; i < 4; ++i) {
                int c = tid + i * 256;
                int row = c >> 3, kc = (c & 7) * 4;
                *(uint2*)&As[cur ^ 1][row][kc] = pack4_rhu(ax[i]);
                *(uint2*)&Bs[cur ^ 1][row][kc] = pack4_rhu(bx[i]);
            }
        }
        cur ^= 1;
    }
#pragma unroll
    for (int mi = 0; mi < 4; ++mi)
#pragma unroll
        for (int ni = 0; ni < 4; ++ni)
#pragma unroll
            for (int r = 0; r < 4; ++r) {
                int m = m0 + wm * 64 + mi * 16 + lg * 4 + r;
                int n = n0 + wn * 64 + ni * 16 + lc;
                int b = m >> 11, s = m & 2047;
                int h = n >> 6, dh = n & 63;
                qout[(((size_t)b * 16 + h) * 2048 + s) * 64 + dh] = f2bf(acc[mi][ni][r] * QSCALE);
            }
}

// ---------------- fused: k fp32->bf16  AND  v fp32 [B,H,S,DH] -> bf16 [B,H,DH,S] ----------------
__global__ __launch_bounds__(256) void convtrans_kernel(const float* __restrict__ kin,
                                                        const float* __restrict__ vin,
                                                        unsigned short* __restrict__ kb,
                                                        unsigned short* __restrict__ vt) {
    __shared__ float buf[64][65];
    const int bid = blockIdx.x;
    const int tid = threadIdx.x;
    if (bid < 8192) {
        int i = bid * 256 + tid;
        float4 v = ((const float4*)kin)[i];
        u16x4 o = { f2bf(v.x), f2bf(v.y), f2bf(v.z), f2bf(v.w) };
        ((u16x4*)kb)[i] = o;
    } else {
        const int idx = bid - 8192;
        const int s0 = (idx & 31) * 64;
        const int bh = idx >> 5;
#pragma unroll
        for (int i = 0; i < 4; ++i) {
            int c = tid + i * 256;
            int s = c >> 4, dc = (c & 15) * 4;
            float4 val = *(const float4*)(vin + ((size_t)bh * 2048 + s0 + s) * 64 + dc);
            buf[s][dc] = val.x; buf[s][dc + 1] = val.y; buf[s][dc + 2] = val.z; buf[s][dc + 3] = val.w;
        }
        __syncthreads();
#pragma unroll
        for (int i = 0; i < 4; ++i) {
            int c = tid + i * 256;
            int dh = c >> 4, sc = (c & 15) * 4;
            u16x4 o = { f2bf(buf[sc][dh]), f2bf(buf[sc + 1][dh]), f2bf(buf[sc + 2][dh]), f2bf(buf[sc + 3][dh]) };
            *(u16x4*)(vt + ((size_t)bh * 64 + dh) * 2048 + s0 + sc) = o;
        }
    }
}

// ---------------- fused causal flash attention + residual ----------------
// grid: (64 bh, 16), qb = 15 - blockIdx.y -> LPT dispatch. 256 threads (4 waves
// x 32 q-rows). LDS padded to 48KB -> deterministic 3 blocks/CU backfill queue
// (R10-proven residency). P-transpose for PV IN REGISTERS (permlane32/16_swap,
// no Ps LDS, conflicts=0). l computed via ones-MFMA accumulated in C operand
// (no VALU sum, no epilogue shuffles). No-max exp2 softmax, vec4 epilogue.
__global__ __launch_bounds__(256) void attn_kernel(const unsigned short* __restrict__ qg,
                                                   const unsigned short* __restrict__ kg,
                                                   const unsigned short* __restrict__ vtg,
                                                   const float* __restrict__ x,
                                                   float* __restrict__ outp) {
    __shared__ __align__(16) unsigned short Ks[2][64][64];
    __shared__ __align__(16) unsigned short VTs[2][64][64];
    __shared__ unsigned short LdsPad[8192];   // occupancy control: 48KB total -> 3 blocks/CU

    const int bh = blockIdx.x;
    const int qb = 15 - blockIdx.y;
    const int b = bh >> 4, h = bh & 15;
    const int tid = threadIdx.x;
    const int wave = tid >> 6, lane = tid & 63;
    const int lg = lane >> 4, lc = lane & 15;
    const int lc7 = lc & 7;
    const int qw0 = qb * 128 + wave * 32;
    const int nkv = 2 * qb + 2;

    if (tid >= 0x10000) LdsPad[tid] = 0;   // never true; keeps pad allocated

    // staging: 256 threads cover 512 chunks of K and VT (2 rows each, same c16)
    const int r0  = tid >> 3;            // 0..31
    const int c16 = tid & 7;
    const int swz = (c16 ^ (r0 & 7)) * 8;    // same for r0+32 (low 3 bits equal)
    const unsigned short* kbase = kg  + ((size_t)bh * 2048 + r0) * 64 + c16 * 8;
    const unsigned short* vbase = vtg + ((size_t)bh * 64 + r0) * 2048 + c16 * 8;

    // Q B-frags in registers: qf[qt][c] = Q[qw0+qt*16+lc][c*32 + lg*8 ..]
    bf16x8 qf[2][2];
#pragma unroll
    for (int qt = 0; qt < 2; ++qt)
#pragma unroll
        for (int c = 0; c < 2; ++c)
            qf[qt][c] = *(const bf16x8*)(qg + ((size_t)bh * 2048 + qw0 + qt * 16 + lc) * 64 + c * 32 + lg * 8);

    // ones A-frag for the l-MFMA (bf16 1.0 broadcast)
    bf16x8 ones;
#pragma unroll
    for (int i = 0; i < 8; ++i) ones[i] = (short)0x3F80;

    f32x4 oacc[2][4];   // O^T: col=lc=q-local, row=lg*4+r=dh-local
    f32x4 lacc[2];      // every row = running sum_k P[k][q=lc]
#pragma unroll
    for (int qt = 0; qt < 2; ++qt) {
#pragma unroll
        for (int dt = 0; dt < 4; ++dt) oacc[qt][dt] = (f32x4){0.f, 0.f, 0.f, 0.f};
        lacc[qt] = (f32x4){0.f, 0.f, 0.f, 0.f};
    }

    {   // prologue: stage tile 0 into buffer 0
        *(bf16x8*)&Ks[0][r0][swz]       = *(const bf16x8*)(kbase);
        *(bf16x8*)&Ks[0][r0 + 32][swz]  = *(const bf16x8*)(kbase + 2048);
        *(bf16x8*)&VTs[0][r0][swz]      = *(const bf16x8*)(vbase);
        *(bf16x8*)&VTs[0][r0 + 32][swz] = *(const bf16x8*)(vbase + 65536);
    }

    int cur = 0;
    for (int kv = 0; kv < nkv; ++kv) {
        __syncthreads();   // buf[cur] staged & visible; prior readers of buf[cur^1] done

        const bool havenext = (kv + 1 < nkv);
        const int nxt = havenext ? kv + 1 : kv;
        bf16x8 nk0 = *(const bf16x8*)(kbase + (size_t)nxt * 4096);
        bf16x8 nk1 = *(const bf16x8*)(kbase + (size_t)nxt * 4096 + 2048);
        bf16x8 nv0 = *(const bf16x8*)(vbase + nxt * 64);
        bf16x8 nv1 = *(const bf16x8*)(vbase + nxt * 64 + 65536);

        const bool active = (kv * 64 <= qw0 + 31);
        if (active) {
            // K A-frags (shared across both q-tiles)
            bf16x8 kf[4][2];
#pragma unroll
            for (int kt = 0; kt < 4; ++kt)
#pragma unroll
                for (int c = 0; c < 2; ++c)
                    kf[kt][c] = *(const bf16x8*)&Ks[cur][kt * 16 + lc][((4 * c + lg) ^ lc7) * 8];

            const int kvb = kv * 64;
            bf16x8 pf[2][2];   // PV B-frags, built in-register
#pragma unroll
            for (int qt = 0; qt < 2; ++qt) {
                f32x4 st[4];
                __builtin_amdgcn_s_setprio(1);
#pragma unroll
                for (int kt = 0; kt < 4; ++kt) {
                    f32x4 a = (f32x4){0.f, 0.f, 0.f, 0.f};
                    a = MFMA16(kf[kt][0], qf[qt][0], a);
                    a = MFMA16(kf[kt][1], qf[qt][1], a);
                    st[kt] = a;
                }
                __builtin_amdgcn_s_setprio(0);

                // softmax (fixed max=0, exp2 domain); masked -> 0 without exp
                float pe[4][4];
                if (kvb + 63 > qw0 + qt * 16) {   // diagonal tile only
                    const int qrow = qw0 + qt * 16 + lc;
#pragma unroll
                    for (int kt = 0; kt < 4; ++kt)
#pragma unroll
                        for (int r = 0; r < 4; ++r) {
                            int kk = kvb + kt * 16 + lg * 4 + r;
                            pe[kt][r] = (kk > qrow) ? 0.f : exp2_fast(st[kt][r]);
                        }
                } else {
#pragma unroll
                    for (int kt = 0; kt < 4; ++kt)
#pragma unroll
                        for (int r = 0; r < 4; ++r) pe[kt][r] = exp2_fast(st[kt][r]);
                }

                // pack P (truncate) into 8 u32 words
                unsigned Wk[4][2];
#pragma unroll
                for (int kt = 0; kt < 4; ++kt) {
                    Wk[kt][0] = __builtin_amdgcn_perm(__float_as_uint(pe[kt][1]), __float_as_uint(pe[kt][0]), 0x07060302u);
                    Wk[kt][1] = __builtin_amdgcn_perm(__float_as_uint(pe[kt][3]), __float_as_uint(pe[kt][2]), 0x07060302u);
                }
                // in-register transpose: per (c,h): swap32 then swap16
                unsigned T0[4], T1[4];
#pragma unroll
                for (int hh = 0; hh < 2; ++hh) {
                    unsigned a0 = Wk[0][hh], b0 = Wk[1][hh];
                    permswap32(a0, b0);
                    permswap16(a0, b0);
                    T0[hh] = a0; T0[2 + hh] = b0;
                    unsigned a1 = Wk[2][hh], b1 = Wk[3][hh];
                    permswap32(a1, b1);
                    permswap16(a1, b1);
                    T1[hh] = a1; T1[2 + hh] = b1;
                }
                union { u32x4 u; bf16x8 v; } cv0, cv1;
                cv0.u = (u32x4){T0[0], T0[1], T0[2], T0[3]};
                cv1.u = (u32x4){T1[0], T1[1], T1[2], T1[3]};
                pf[qt][0] = cv0.v;
                pf[qt][1] = cv1.v;
            }

            // ---- O^T += V^T P^T (16 MFMA) and l += 1^T P^T (4 MFMA) ----
            __builtin_amdgcn_s_setprio(1);
#pragma unroll
            for (int qt = 0; qt < 2; ++qt) {
                lacc[qt] = MFMA16(ones, pf[qt][0], lacc[qt]);
                lacc[qt] = MFMA16(ones, pf[qt][1], lacc[qt]);
            }
#pragma unroll
            for (int dt = 0; dt < 4; ++dt)
#pragma unroll
                for (int c = 0; c < 2; ++c) {
                    bf16x8 vtf = *(const bf16x8*)&VTs[cur][dt * 16 + lc][((4 * c + lg) ^ lc7) * 8];
#pragma unroll
                    for (int qt = 0; qt < 2; ++qt)
                        oacc[qt][dt] = MFMA16(vtf, pf[qt][c], oacc[qt][dt]);
                }
            __builtin_amdgcn_s_setprio(0);
        }

        // write next tile into the other buffer (nobody reads it until next barrier)
        if (havenext) {
            *(bf16x8*)&Ks[cur ^ 1][r0][swz]       = nk0;
            *(bf16x8*)&Ks[cur ^ 1][r0 + 32][swz]  = nk1;
            *(bf16x8*)&VTs[cur ^ 1][r0][swz]      = nv0;
            *(bf16x8*)&VTs[cur ^ 1][r0 + 32][swz] = nv1;
        }
        cur ^= 1;
    }

    // epilogue: normalize (l already per-lane via ones-MFMA), add residual, vec4 store
#pragma unroll
    for (int qt = 0; qt < 2; ++qt) {
        float li = 1.0f / lacc[qt][0];
        const int q = qw0 + qt * 16 + lc;
        const size_t obase = ((size_t)b * 2048 + q) * 1024 + (size_t)h * 64 + lg * 4;
#pragma unroll
        for (int dt = 0; dt < 4; ++dt) {
            const size_t oi = obase + dt * 16;
            float4 xv = *(const float4*)(x + oi);
            float4 ov;
            ov.x = xv.x + oacc[qt][dt][0] * li;
            ov.y = xv.y + oacc[qt][dt][1] * li;
            ov.z = xv.z + oacc[qt][dt][2] * li;
            ov.w = xv.w + oacc[qt][dt][3] * li;
            *(float4*)(outp + oi) = ov;
        }
    }
}

extern "C" void kernel_launch(void* const* d_in, const int* in_sizes, int n_in,
                              void* d_out, int out_size, void* d_ws, size_t ws_size,
                              hipStream_t stream) {
    const float* x  = (const float*)d_in[0];
    const float* k  = (const float*)d_in[1];
    const float* v  = (const float*)d_in[2];
    const float* wq = (const float*)d_in[3];
    float* outp = (float*)d_out;

    const size_t NELEM = (size_t)4 * 2048 * 1024;
    unsigned short* qbuf = (unsigned short*)d_ws;
    unsigned short* kbuf = qbuf + NELEM;
    unsigned short* vtbuf = kbuf + NELEM;

    qproj_kernel<<<dim3(64, 8), 256, 0, stream>>>(x, wq, qbuf);
    convtrans_kernel<<<8192 + 2048, 256, 0, stream>>>(k, v, kbuf, vtbuf);
    attn_kernel<<<dim3(64, 16), 256, 0, stream>>>(qbuf, kbuf, vtbuf, x, outp);
}

// Round 13
// 111.878 us; speedup vs baseline: 1.0003x; 1.0003x over previous
//
#include <hip/hip_runtime.h>
#include <hip/hip_bf16.h>

// B=4, S=2048, D=1024, H=16, DH=64
typedef __attribute__((ext_vector_type(4))) float f32x4;
typedef __attribute__((ext_vector_type(8))) short bf16x8;
typedef __attribute__((ext_vector_type(4))) unsigned short u16x4;
typedef __attribute__((ext_vector_type(4))) unsigned int u32x4;

#define MFMA16(a, b, c) __builtin_amdgcn_mfma_f32_16x16x32_bf16((a), (b), (c), 0, 0, 0)

static __device__ __forceinline__ unsigned short f2bf(float f) {
    unsigned u = __float_as_uint(f);
    u += 0x7FFFu + ((u >> 16) & 1u);   // RNE
    return (unsigned short)(u >> 16);
}
// pack 4 floats -> 4 bf16 (round-half-up) as uint2, via v_perm_b32
static __device__ __forceinline__ uint2 pack4_rhu(float4 v) {
    unsigned a = __float_as_uint(v.x) + 0x8000u;
    unsigned b = __float_as_uint(v.y) + 0x8000u;
    unsigned c = __float_as_uint(v.z) + 0x8000u;
    unsigned d = __float_as_uint(v.w) + 0x8000u;
    uint2 r;
    r.x = __builtin_amdgcn_perm(b, a, 0x07060302u);
    r.y = __builtin_amdgcn_perm(d, c, 0x07060302u);
    return r;
}
static __device__ __forceinline__ float exp2_fast(float x) {
#if __has_builtin(__builtin_amdgcn_exp2f)
    return __builtin_amdgcn_exp2f(x);
#else
    return exp2f(x);
#endif
}

// vdst.hi32 <-> vsrc.lo32
static __device__ __forceinline__ void permswap32(unsigned &a, unsigned &b) {
#if __has_builtin(__builtin_amdgcn_permlane32_swap)
    typedef __attribute__((ext_vector_type(2))) unsigned u32x2_t;
    u32x2_t r = __builtin_amdgcn_permlane32_swap(a, b, false, false);
    a = r[0]; b = r[1];
#else
    asm volatile("v_permlane32_swap_b32 %0, %1" : "+v"(a), "+v"(b));
#endif
}
// vdst.row1 <-> vsrc.row0, vdst.row3 <-> vsrc.row2  (row = 16 lanes)
static __device__ __forceinline__ void permswap16(unsigned &a, unsigned &b) {
#if __has_builtin(__builtin_amdgcn_permlane16_swap)
    typedef __attribute__((ext_vector_type(2))) unsigned u32x2_t;
    u32x2_t r = __builtin_amdgcn_permlane16_swap(a, b, false, false);
    a = r[0]; b = r[1];
#else
    asm volatile("v_permlane16_swap_b32 %0, %1" : "+v"(a), "+v"(b));
#endif
}

// scores premultiplied so softmax runs in exp2 domain: c = log2(e)/32
#define QSCALE 0.04508422002778011f

// ---------------- Q projection: q = (x @ Wq^T) * QSCALE, bf16 [B,H,S,DH] ----------------
__global__ __launch_bounds__(256) void qproj_kernel(const float* __restrict__ x,
                                                    const float* __restrict__ wq,
                                                    unsigned short* __restrict__ qout) {
    __shared__ __align__(16) unsigned short As[2][128][40];
    __shared__ __align__(16) unsigned short Bs[2][128][40];
    const int m0 = blockIdx.x * 128;
    const int n0 = blockIdx.y * 128;
    const int tid = threadIdx.x;
    const int wave = tid >> 6, lane = tid & 63;
    const int lg = lane >> 4, lc = lane & 15;
    const int wm = wave >> 1, wn = wave & 1;

    f32x4 acc[4][4];
#pragma unroll
    for (int i = 0; i < 4; ++i)
#pragma unroll
        for (int j = 0; j < 4; ++j) acc[i][j] = (f32x4){0.f, 0.f, 0.f, 0.f};

    float4 ax[4], bx[4];
#pragma unroll
    for (int i = 0; i < 4; ++i) {
        int c = tid + i * 256;
        int row = c >> 3, kc = (c & 7) * 4;
        ax[i] = *(const float4*)(x  + (size_t)(m0 + row) * 1024 + kc);
        bx[i] = *(const float4*)(wq + (size_t)(n0 + row) * 1024 + kc);
    }
#pragma unroll
    for (int i = 0; i < 4; ++i) {
        int c = tid + i * 256;
        int row = c >> 3, kc = (c & 7) * 4;
        *(uint2*)&As[0][row][kc] = pack4_rhu(ax[i]);
        *(uint2*)&Bs[0][row][kc] = pack4_rhu(bx[i]);
    }

    int cur = 0;
    for (int ki = 0; ki < 32; ++ki) {
        __syncthreads();
        const bool havenext = (ki + 1 < 32);
        if (havenext) {
            int ks = (ki + 1) * 32;
#pragma unroll
            for (int i = 0; i < 4; ++i) {
                int c = tid + i * 256;
                int row = c >> 3, kc = (c & 7) * 4;
                ax[i] = *(const float4*)(x  + (size_t)(m0 + row) * 1024 + ks + kc);
                bx[i] = *(const float4*)(wq + (size_t)(n0 + row) * 1024 + ks + kc);
            }
        }
        bf16x8 af[4], bfr[4];
#pragma unroll
        for (int i = 0; i < 4; ++i) {
            af[i]  = *(const bf16x8*)&As[cur][wm * 64 + i * 16 + lc][lg * 8];
            bfr[i] = *(const bf16x8*)&Bs[cur][wn * 64 + i * 16 + lc][lg * 8];
        }
        __builtin_amdgcn_s_setprio(1);
#pragma unroll
        for (int mi = 0; mi < 4; ++mi)
#pragma unroll
            for (int ni = 0; ni < 4; ++ni)
                acc[mi][ni] = MFMA16(af[mi], bfr[ni], acc[mi][ni]);
        __builtin_amdgcn_s_setprio(0);
        if (havenext) {
#pragma unroll
            for (int i = 0; i < 4; ++i) {
                int c = tid + i * 256;
                int row = c >> 3, kc = (c & 7) * 4;
                *(uint2*)&As[cur ^ 1][row][kc] = pack4_rhu(ax[i]);
                *(uint2*)&Bs[cur ^ 1][row][kc] = pack4_rhu(bx[i]);
            }
        }
        cur ^= 1;
    }
#pragma unroll
    for (int mi = 0; mi < 4; ++mi)
#pragma unroll
        for (int ni = 0; ni < 4; ++ni)
#pragma unroll
            for (int r = 0; r < 4; ++r) {
                int m = m0 + wm * 64 + mi * 16 + lg * 4 + r;
                int n = n0 + wn * 64 + ni * 16 + lc;
                int b = m >> 11, s = m & 2047;
                int h = n >> 6, dh = n & 63;
                qout[(((size_t)b * 16 + h) * 2048 + s) * 64 + dh] = f2bf(acc[mi][ni][r] * QSCALE);
            }
}

// ---------------- fused: k fp32->bf16  AND  v fp32 [B,H,S,DH] -> bf16 [B,H,DH,S] ----------------
__global__ __launch_bounds__(256) void convtrans_kernel(const float* __restrict__ kin,
                                                        const float* __restrict__ vin,
                                                        unsigned short* __restrict__ kb,
                                                        unsigned short* __restrict__ vt) {
    __shared__ float buf[64][65];
    const int bid = blockIdx.x;
    const int tid = threadIdx.x;
    if (bid < 8192) {
        int i = bid * 256 + tid;
        float4 v = ((const float4*)kin)[i];
        u16x4 o = { f2bf(v.x), f2bf(v.y), f2bf(v.z), f2bf(v.w) };
        ((u16x4*)kb)[i] = o;
    } else {
        const int idx = bid - 8192;
        const int s0 = (idx & 31) * 64;
        const int bh = idx >> 5;
#pragma unroll
        for (int i = 0; i < 4; ++i) {
            int c = tid + i * 256;
            int s = c >> 4, dc = (c & 15) * 4;
            float4 val = *(const float4*)(vin + ((size_t)bh * 2048 + s0 + s) * 64 + dc);
            buf[s][dc] = val.x; buf[s][dc + 1] = val.y; buf[s][dc + 2] = val.z; buf[s][dc + 3] = val.w;
        }
        __syncthreads();
#pragma unroll
        for (int i = 0; i < 4; ++i) {
            int c = tid + i * 256;
            int dh = c >> 4, sc = (c & 15) * 4;
            u16x4 o = { f2bf(buf[sc][dh]), f2bf(buf[sc + 1][dh]), f2bf(buf[sc + 2][dh]), f2bf(buf[sc + 3][dh]) };
            *(u16x4*)(vt + ((size_t)bh * 64 + dh) * 2048 + s0 + sc) = o;
        }
    }
}

// ---------------- fused causal flash attention + residual ----------------
// grid: (64 bh, 16), qb = 15 - blockIdx.y -> LPT dispatch. 256 threads (4 waves
// x 32 q-rows). 32KB static LDS + 16KB DYNAMIC pad (runtime-allocated, cannot be
// DCE'd) = 48KB -> deterministic 3 blocks/CU backfill queue (R10-proven).
// P-transpose for PV IN REGISTERS (permlane32/16_swap, no Ps LDS, conflicts=0).
// l via ones-MFMA in C operand (no VALU sum, no epilogue shuffles).
// No-max exp2 softmax, vec4 epilogue.
__global__ __launch_bounds__(256) void attn_kernel(const unsigned short* __restrict__ qg,
                                                   const unsigned short* __restrict__ kg,
                                                   const unsigned short* __restrict__ vtg,
                                                   const float* __restrict__ x,
                                                   float* __restrict__ outp) {
    __shared__ __align__(16) unsigned short Ks[2][64][64];
    __shared__ __align__(16) unsigned short VTs[2][64][64];
    extern __shared__ unsigned short DynPad[];   // 16KB at launch: occupancy control

    const int bh = blockIdx.x;
    const int qb = 15 - blockIdx.y;
    const int b = bh >> 4, h = bh & 15;
    const int tid = threadIdx.x;
    const int wave = tid >> 6, lane = tid & 63;
    const int lg = lane >> 4, lc = lane & 15;
    const int lc7 = lc & 7;
    const int qw0 = qb * 128 + wave * 32;
    const int nkv = 2 * qb + 2;
    (void)DynPad;

    // staging: 256 threads cover 512 chunks of K and VT (2 rows each, same c16)
    const int r0  = tid >> 3;            // 0..31
    const int c16 = tid & 7;
    const int swz = (c16 ^ (r0 & 7)) * 8;    // same for r0+32 (low 3 bits equal)
    const unsigned short* kbase = kg  + ((size_t)bh * 2048 + r0) * 64 + c16 * 8;
    const unsigned short* vbase = vtg + ((size_t)bh * 64 + r0) * 2048 + c16 * 8;

    // Q B-frags in registers: qf[qt][c] = Q[qw0+qt*16+lc][c*32 + lg*8 ..]
    bf16x8 qf[2][2];
#pragma unroll
    for (int qt = 0; qt < 2; ++qt)
#pragma unroll
        for (int c = 0; c < 2; ++c)
            qf[qt][c] = *(const bf16x8*)(qg + ((size_t)bh * 2048 + qw0 + qt * 16 + lc) * 64 + c * 32 + lg * 8);

    // ones A-frag for the l-MFMA (bf16 1.0 broadcast)
    bf16x8 ones;
#pragma unroll
    for (int i = 0; i < 8; ++i) ones[i] = (short)0x3F80;

    f32x4 oacc[2][4];   // O^T: col=lc=q-local, row=lg*4+r=dh-local
    f32x4 lacc[2];      // every row = running sum_k P[k][q=lc]
#pragma unroll
    for (int qt = 0; qt < 2; ++qt) {
#pragma unroll
        for (int dt = 0; dt < 4; ++dt) oacc[qt][dt] = (f32x4){0.f, 0.f, 0.f, 0.f};
        lacc[qt] = (f32x4){0.f, 0.f, 0.f, 0.f};
    }

    {   // prologue: stage tile 0 into buffer 0
        *(bf16x8*)&Ks[0][r0][swz]       = *(const bf16x8*)(kbase);
        *(bf16x8*)&Ks[0][r0 + 32][swz]  = *(const bf16x8*)(kbase + 2048);
        *(bf16x8*)&VTs[0][r0][swz]      = *(const bf16x8*)(vbase);
        *(bf16x8*)&VTs[0][r0 + 32][swz] = *(const bf16x8*)(vbase + 65536);
    }

    int cur = 0;
    for (int kv = 0; kv < nkv; ++kv) {
        __syncthreads();   // buf[cur] staged & visible; prior readers of buf[cur^1] done

        const bool havenext = (kv + 1 < nkv);
        const int nxt = havenext ? kv + 1 : kv;
        bf16x8 nk0 = *(const bf16x8*)(kbase + (size_t)nxt * 4096);
        bf16x8 nk1 = *(const bf16x8*)(kbase + (size_t)nxt * 4096 + 2048);
        bf16x8 nv0 = *(const bf16x8*)(vbase + nxt * 64);
        bf16x8 nv1 = *(const bf16x8*)(vbase + nxt * 64 + 65536);

        const bool active = (kv * 64 <= qw0 + 31);
        if (active) {
            // K A-frags (shared across both q-tiles)
            bf16x8 kf[4][2];
#pragma unroll
            for (int kt = 0; kt < 4; ++kt)
#pragma unroll
                for (int c = 0; c < 2; ++c)
                    kf[kt][c] = *(const bf16x8*)&Ks[cur][kt * 16 + lc][((4 * c + lg) ^ lc7) * 8];

            const int kvb = kv * 64;
            bf16x8 pf[2][2];   // PV B-frags, built in-register
#pragma unroll
            for (int qt = 0; qt < 2; ++qt) {
                f32x4 st[4];
                __builtin_amdgcn_s_setprio(1);
#pragma unroll
                for (int kt = 0; kt < 4; ++kt) {
                    f32x4 a = (f32x4){0.f, 0.f, 0.f, 0.f};
                    a = MFMA16(kf[kt][0], qf[qt][0], a);
                    a = MFMA16(kf[kt][1], qf[qt][1], a);
                    st[kt] = a;
                }
                __builtin_amdgcn_s_setprio(0);

                // softmax (fixed max=0, exp2 domain); masked -> 0 without exp
                float pe[4][4];
                if (kvb + 63 > qw0 + qt * 16) {   // diagonal tile only
                    const int qrow = qw0 + qt * 16 + lc;
#pragma unroll
                    for (int kt = 0; kt < 4; ++kt)
#pragma unroll
                        for (int r = 0; r < 4; ++r) {
                            int kk = kvb + kt * 16 + lg * 4 + r;
                            pe[kt][r] = (kk > qrow) ? 0.f : exp2_fast(st[kt][r]);
                        }
                } else {
#pragma unroll
                    for (int kt = 0; kt < 4; ++kt)
#pragma unroll
                        for (int r = 0; r < 4; ++r) pe[kt][r] = exp2_fast(st[kt][r]);
                }

                // pack P (truncate) into 8 u32 words
                unsigned Wk[4][2];
#pragma unroll
                for (int kt = 0; kt < 4; ++kt) {
                    Wk[kt][0] = __builtin_amdgcn_perm(__float_as_uint(pe[kt][1]), __float_as_uint(pe[kt][0]), 0x07060302u);
                    Wk[kt][1] = __builtin_amdgcn_perm(__float_as_uint(pe[kt][3]), __float_as_uint(pe[kt][2]), 0x07060302u);
                }
                // in-register transpose: per (c,h): swap32 then swap16
                unsigned T0[4], T1[4];
#pragma unroll
                for (int hh = 0; hh < 2; ++hh) {
                    unsigned a0 = Wk[0][hh], b0 = Wk[1][hh];
                    permswap32(a0, b0);
                    permswap16(a0, b0);
                    T0[hh] = a0; T0[2 + hh] = b0;
                    unsigned a1 = Wk[2][hh], b1 = Wk[3][hh];
                    permswap32(a1, b1);
                    permswap16(a1, b1);
                    T1[hh] = a1; T1[2 + hh] = b1;
                }
                union { u32x4 u; bf16x8 v; } cv0, cv1;
                cv0.u = (u32x4){T0[0], T0[1], T0[2], T0[3]};
                cv1.u = (u32x4){T1[0], T1[1], T1[2], T1[3]};
                pf[qt][0] = cv0.v;
                pf[qt][1] = cv1.v;
            }

            // ---- O^T += V^T P^T (16 MFMA) and l += 1^T P^T (4 MFMA) ----
            __builtin_amdgcn_s_setprio(1);
#pragma unroll
            for (int qt = 0; qt < 2; ++qt) {
                lacc[qt] = MFMA16(ones, pf[qt][0], lacc[qt]);
                lacc[qt] = MFMA16(ones, pf[qt][1], lacc[qt]);
            }
#pragma unroll
            for (int dt = 0; dt < 4; ++dt)
#pragma unroll
                for (int c = 0; c < 2; ++c) {
                    bf16x8 vtf = *(const bf16x8*)&VTs[cur][dt * 16 + lc][((4 * c + lg) ^ lc7) * 8];
#pragma unroll
                    for (int qt = 0; qt < 2; ++qt)
                        oacc[qt][dt] = MFMA16(vtf, pf[qt][c], oacc[qt][dt]);
                }
            __builtin_amdgcn_s_setprio(0);
        }

        // write next tile into the other buffer (nobody reads it until next barrier)
        if (havenext) {
            *(bf16x8*)&Ks[cur ^ 1][r0][swz]       = nk0;
            *(bf16x8*)&Ks[cur ^ 1][r0 + 32][swz]  = nk1;
            *(bf16x8*)&VTs[cur ^ 1][r0][swz]      = nv0;
            *(bf16x8*)&VTs[cur ^ 1][r0 + 32][swz] = nv1;
        }
        cur ^= 1;
    }

    // epilogue: normalize (l already per-lane via ones-MFMA), add residual, vec4 store
#pragma unroll
    for (int qt = 0; qt < 2; ++qt) {
        float li = 1.0f / lacc[qt][0];
        const int q = qw0 + qt * 16 + lc;
        const size_t obase = ((size_t)b * 2048 + q) * 1024 + (size_t)h * 64 + lg * 4;
#pragma unroll
        for (int dt = 0; dt < 4; ++dt) {
            const size_t oi = obase + dt * 16;
            float4 xv = *(const float4*)(x + oi);
            float4 ov;
            ov.x = xv.x + oacc[qt][dt][0] * li;
            ov.y = xv.y + oacc[qt][dt][1] * li;
            ov.z = xv.z + oacc[qt][dt][2] * li;
            ov.w = xv.w + oacc[qt][dt][3] * li;
            *(float4*)(outp + oi) = ov;
        }
    }
}

extern "C" void kernel_launch(void* const* d_in, const int* in_sizes, int n_in,
                              void* d_out, int out_size, void* d_ws, size_t ws_size,
                              hipStream_t stream) {
    const float* x  = (const float*)d_in[0];
    const float* k  = (const float*)d_in[1];
    const float* v  = (const float*)d_in[2];
    const float* wq = (const float*)d_in[3];
    float* outp = (float*)d_out;

    const size_t NELEM = (size_t)4 * 2048 * 1024;
    unsigned short* qbuf = (unsigned short*)d_ws;
    unsigned short* kbuf = qbuf + NELEM;
    unsigned short* vtbuf = kbuf + NELEM;

    qproj_kernel<<<dim3(64, 8), 256, 0, stream>>>(x, wq, qbuf);
    convtrans_kernel<<<8192 + 2048, 256, 0, stream>>>(k, v, kbuf, vtbuf);
    // 16KB dynamic LDS pad -> 48KB/dispatch -> 3 blocks/CU backfill queue
    attn_kernel<<<dim3(64, 16), 256, 16384, stream>>>(qbuf, kbuf, vtbuf, x, outp);
}

// Round 14
// 111.534 us; speedup vs baseline: 1.0034x; 1.0031x over previous
//
#include <hip/hip_runtime.h>
#include <hip/hip_bf16.h>

// B=4, S=2048, D=1024, H=16, DH=64
typedef __attribute__((ext_vector_type(4))) float f32x4;
typedef __attribute__((ext_vector_type(8))) short bf16x8;
typedef __attribute__((ext_vector_type(4))) unsigned short u16x4;
typedef __attribute__((ext_vector_type(4))) unsigned int u32x4;

#define MFMA16(a, b, c) __builtin_amdgcn_mfma_f32_16x16x32_bf16((a), (b), (c), 0, 0, 0)

static __device__ __forceinline__ unsigned short f2bf(float f) {
    unsigned u = __float_as_uint(f);
    u += 0x7FFFu + ((u >> 16) & 1u);   // RNE
    return (unsigned short)(u >> 16);
}
// pack 4 floats -> 4 bf16 (round-half-up) as uint2, via v_perm_b32
static __device__ __forceinline__ uint2 pack4_rhu(float4 v) {
    unsigned a = __float_as_uint(v.x) + 0x8000u;
    unsigned b = __float_as_uint(v.y) + 0x8000u;
    unsigned c = __float_as_uint(v.z) + 0x8000u;
    unsigned d = __float_as_uint(v.w) + 0x8000u;
    uint2 r;
    r.x = __builtin_amdgcn_perm(b, a, 0x07060302u);
    r.y = __builtin_amdgcn_perm(d, c, 0x07060302u);
    return r;
}
static __device__ __forceinline__ float exp2_fast(float x) {
#if __has_builtin(__builtin_amdgcn_exp2f)
    return __builtin_amdgcn_exp2f(x);
#else
    return exp2f(x);
#endif
}

// vdst.hi32 <-> vsrc.lo32
static __device__ __forceinline__ void permswap32(unsigned &a, unsigned &b) {
#if __has_builtin(__builtin_amdgcn_permlane32_swap)
    typedef __attribute__((ext_vector_type(2))) unsigned u32x2_t;
    u32x2_t r = __builtin_amdgcn_permlane32_swap(a, b, false, false);
    a = r[0]; b = r[1];
#else
    asm volatile("v_permlane32_swap_b32 %0, %1" : "+v"(a), "+v"(b));
#endif
}
// vdst.row1 <-> vsrc.row0, vdst.row3 <-> vsrc.row2  (row = 16 lanes)
static __device__ __forceinline__ void permswap16(unsigned &a, unsigned &b) {
#if __has_builtin(__builtin_amdgcn_permlane16_swap)
    typedef __attribute__((ext_vector_type(2))) unsigned u32x2_t;
    u32x2_t r = __builtin_amdgcn_permlane16_swap(a, b, false, false);
    a = r[0]; b = r[1];
#else
    asm volatile("v_permlane16_swap_b32 %0, %1" : "+v"(a), "+v"(b));
#endif
}

// scores premultiplied so softmax runs in exp2 domain: c = log2(e)/32
#define QSCALE 0.04508422002778011f

// ---------------- Q projection: q = (x @ Wq^T) * QSCALE, bf16 [B,H,S,DH] ----------------
__global__ __launch_bounds__(256) void qproj_kernel(const float* __restrict__ x,
                                                    const float* __restrict__ wq,
                                                    unsigned short* __restrict__ qout) {
    __shared__ __align__(16) unsigned short As[2][128][40];
    __shared__ __align__(16) unsigned short Bs[2][128][40];
    const int m0 = blockIdx.x * 128;
    const int n0 = blockIdx.y * 128;
    const int tid = threadIdx.x;
    const int wave = tid >> 6, lane = tid & 63;
    const int lg = lane >> 4, lc = lane & 15;
    const int wm = wave >> 1, wn = wave & 1;

    f32x4 acc[4][4];
#pragma unroll
    for (int i = 0; i < 4; ++i)
#pragma unroll
        for (int j = 0; j < 4; ++j) acc[i][j] = (f32x4){0.f, 0.f, 0.f, 0.f};

    float4 ax[4], bx[4];
#pragma unroll
    for (int i = 0; i < 4; ++i) {
        int c = tid + i * 256;
        int row = c >> 3, kc = (c & 7) * 4;
        ax[i] = *(const float4*)(x  + (size_t)(m0 + row) * 1024 + kc);
        bx[i] = *(const float4*)(wq + (size_t)(n0 + row) * 1024 + kc);
    }
#pragma unroll
    for (int i = 0; i < 4; ++i) {
        int c = tid + i * 256;
        int row = c >> 3, kc = (c & 7) * 4;
        *(uint2*)&As[0][row][kc] = pack4_rhu(ax[i]);
        *(uint2*)&Bs[0][row][kc] = pack4_rhu(bx[i]);
    }

    int cur = 0;
    for (int ki = 0; ki < 32; ++ki) {
        __syncthreads();
        const bool havenext = (ki + 1 < 32);
        if (havenext) {
            int ks = (ki + 1) * 32;
#pragma unroll
            for (int i = 0; i < 4; ++i) {
                int c = tid + i * 256;
                int row = c >> 3, kc = (c & 7) * 4;
                ax[i] = *(const float4*)(x  + (size_t)(m0 + row) * 1024 + ks + kc);
                bx[i] = *(const float4*)(wq + (size_t)(n0 + row) * 1024 + ks + kc);
            }
        }
        bf16x8 af[4], bfr[4];
#pragma unroll
        for (int i = 0; i < 4; ++i) {
            af[i]  = *(const bf16x8*)&As[cur][wm * 64 + i * 16 + lc][lg * 8];
            bfr[i] = *(const bf16x8*)&Bs[cur][wn * 64 + i * 16 + lc][lg * 8];
        }
        __builtin_amdgcn_s_setprio(1);
#pragma unroll
        for (int mi = 0; mi < 4; ++mi)
#pragma unroll
            for (int ni = 0; ni < 4; ++ni)
                acc[mi][ni] = MFMA16(af[mi], bfr[ni], acc[mi][ni]);
        __builtin_amdgcn_s_setprio(0);
        if (havenext) {
#pragma unroll
            for (int i = 0; i < 4; ++i) {
                int c = tid + i * 256;
                int row = c >> 3, kc = (c & 7) * 4;
                *(uint2*)&As[cur ^ 1][row][kc] = pack4_rhu(ax[i]);
                *(uint2*)&Bs[cur ^ 1][row][kc] = pack4_rhu(bx[i]);
            }
        }
        cur ^= 1;
    }
#pragma unroll
    for (int mi = 0; mi < 4; ++mi)
#pragma unroll
        for (int ni = 0; ni < 4; ++ni)
#pragma unroll
            for (int r = 0; r < 4; ++r) {
                int m = m0 + wm * 64 + mi * 16 + lg * 4 + r;
                int n = n0 + wn * 64 + ni * 16 + lc;
                int b = m >> 11, s = m & 2047;
                int h = n >> 6, dh = n & 63;
                qout[(((size_t)b * 16 + h) * 2048 + s) * 64 + dh] = f2bf(acc[mi][ni][r] * QSCALE);
            }
}

// ---------------- fused: k fp32->bf16  AND  v fp32 [B,H,S,DH] -> bf16 [B,H,DH,S] ----------------
__global__ __launch_bounds__(256) void convtrans_kernel(const float* __restrict__ kin,
                                                        const float* __restrict__ vin,
                                                        unsigned short* __restrict__ kb,
                                                        unsigned short* __restrict__ vt) {
    __shared__ float buf[64][65];
    const int bid = blockIdx.x;
    const int tid = threadIdx.x;
    if (bid < 8192) {
        int i = bid * 256 + tid;
        float4 v = ((const float4*)kin)[i];
        u16x4 o = { f2bf(v.x), f2bf(v.y), f2bf(v.z), f2bf(v.w) };
        ((u16x4*)kb)[i] = o;
    } else {
        const int idx = bid - 8192;
        const int s0 = (idx & 31) * 64;
        const int bh = idx >> 5;
#pragma unroll
        for (int i = 0; i < 4; ++i) {
            int c = tid + i * 256;
            int s = c >> 4, dc = (c & 15) * 4;
            float4 val = *(const float4*)(vin + ((size_t)bh * 2048 + s0 + s) * 64 + dc);
            buf[s][dc] = val.x; buf[s][dc + 1] = val.y; buf[s][dc + 2] = val.z; buf[s][dc + 3] = val.w;
        }
        __syncthreads();
#pragma unroll
        for (int i = 0; i < 4; ++i) {
            int c = tid + i * 256;
            int dh = c >> 4, sc = (c & 15) * 4;
            u16x4 o = { f2bf(buf[sc][dh]), f2bf(buf[sc + 1][dh]), f2bf(buf[sc + 2][dh]), f2bf(buf[sc + 3][dh]) };
            *(u16x4*)(vt + ((size_t)bh * 64 + dh) * 2048 + s0 + sc) = o;
        }
    }
}

// ---------------- fused causal flash attention + residual ----------------
// grid: (64 bh, 16), qb = 15 - blockIdx.y -> LPT dispatch. 256 threads (4 waves
// x 32 q-rows). 32KB working LDS + 16KB OccPad kept alive by a VOLATILE store
// (cannot be DCE'd -> really allocated) = 48KB -> 3 blocks/CU backfill queue
// (R10-proven residency). P-transpose for PV IN REGISTERS (permlane32/16_swap,
// no Ps LDS, conflicts=0). l via ones-MFMA in C operand. No-max exp2 softmax,
// vec4 epilogue.
__global__ __launch_bounds__(256) void attn_kernel(const unsigned short* __restrict__ qg,
                                                   const unsigned short* __restrict__ kg,
                                                   const unsigned short* __restrict__ vtg,
                                                   const float* __restrict__ x,
                                                   float* __restrict__ outp) {
    __shared__ __align__(16) unsigned short Ks[2][64][64];
    __shared__ __align__(16) unsigned short VTs[2][64][64];
    __shared__ __align__(16) unsigned short OccPad[8192];   // 16KB occupancy control

    const int bh = blockIdx.x;
    const int qb = 15 - blockIdx.y;
    const int b = bh >> 4, h = bh & 15;
    const int tid = threadIdx.x;
    const int wave = tid >> 6, lane = tid & 63;
    const int lg = lane >> 4, lc = lane & 15;
    const int lc7 = lc & 7;
    const int qw0 = qb * 128 + wave * 32;
    const int nkv = 2 * qb + 2;

    // volatile store: cannot be eliminated -> OccPad is truly allocated (48KB/block)
    ((volatile unsigned short*)OccPad)[tid] = 0;

    // staging: 256 threads cover 512 chunks of K and VT (2 rows each, same c16)
    const int r0  = tid >> 3;            // 0..31
    const int c16 = tid & 7;
    const int swz = (c16 ^ (r0 & 7)) * 8;    // same for r0+32 (low 3 bits equal)
    const unsigned short* kbase = kg  + ((size_t)bh * 2048 + r0) * 64 + c16 * 8;
    const unsigned short* vbase = vtg + ((size_t)bh * 64 + r0) * 2048 + c16 * 8;

    // Q B-frags in registers: qf[qt][c] = Q[qw0+qt*16+lc][c*32 + lg*8 ..]
    bf16x8 qf[2][2];
#pragma unroll
    for (int qt = 0; qt < 2; ++qt)
#pragma unroll
        for (int c = 0; c < 2; ++c)
            qf[qt][c] = *(const bf16x8*)(qg + ((size_t)bh * 2048 + qw0 + qt * 16 + lc) * 64 + c * 32 + lg * 8);

    // ones A-frag for the l-MFMA (bf16 1.0 broadcast)
    bf16x8 ones;
#pragma unroll
    for (int i = 0; i < 8; ++i) ones[i] = (short)0x3F80;

    f32x4 oacc[2][4];   // O^T: col=lc=q-local, row=lg*4+r=dh-local
    f32x4 lacc[2];      // every row = running sum_k P[k][q=lc]
#pragma unroll
    for (int qt = 0; qt < 2; ++qt) {
#pragma unroll
        for (int dt = 0; dt < 4; ++dt) oacc[qt][dt] = (f32x4){0.f, 0.f, 0.f, 0.f};
        lacc[qt] = (f32x4){0.f, 0.f, 0.f, 0.f};
    }

    {   // prologue: stage tile 0 into buffer 0
        *(bf16x8*)&Ks[0][r0][swz]       = *(const bf16x8*)(kbase);
        *(bf16x8*)&Ks[0][r0 + 32][swz]  = *(const bf16x8*)(kbase + 2048);
        *(bf16x8*)&VTs[0][r0][swz]      = *(const bf16x8*)(vbase);
        *(bf16x8*)&VTs[0][r0 + 32][swz] = *(const bf16x8*)(vbase + 65536);
    }

    int cur = 0;
    for (int kv = 0; kv < nkv; ++kv) {
        __syncthreads();   // buf[cur] staged & visible; prior readers of buf[cur^1] done

        const bool havenext = (kv + 1 < nkv);
        const int nxt = havenext ? kv + 1 : kv;
        bf16x8 nk0 = *(const bf16x8*)(kbase + (size_t)nxt * 4096);
        bf16x8 nk1 = *(const bf16x8*)(kbase + (size_t)nxt * 4096 + 2048);
        bf16x8 nv0 = *(const bf16x8*)(vbase + nxt * 64);
        bf16x8 nv1 = *(const bf16x8*)(vbase + nxt * 64 + 65536);

        const bool active = (kv * 64 <= qw0 + 31);
        if (active) {
            // K A-frags (shared across both q-tiles)
            bf16x8 kf[4][2];
#pragma unroll
            for (int kt = 0; kt < 4; ++kt)
#pragma unroll
                for (int c = 0; c < 2; ++c)
                    kf[kt][c] = *(const bf16x8*)&Ks[cur][kt * 16 + lc][((4 * c + lg) ^ lc7) * 8];

            const int kvb = kv * 64;
            bf16x8 pf[2][2];   // PV B-frags, built in-register
#pragma unroll
            for (int qt = 0; qt < 2; ++qt) {
                f32x4 st[4];
                __builtin_amdgcn_s_setprio(1);
#pragma unroll
                for (int kt = 0; kt < 4; ++kt) {
                    f32x4 a = (f32x4){0.f, 0.f, 0.f, 0.f};
                    a = MFMA16(kf[kt][0], qf[qt][0], a);
                    a = MFMA16(kf[kt][1], qf[qt][1], a);
                    st[kt] = a;
                }
                __builtin_amdgcn_s_setprio(0);

                // softmax (fixed max=0, exp2 domain); masked -> 0 without exp
                float pe[4][4];
                if (kvb + 63 > qw0 + qt * 16) {   // diagonal tile only
                    const int qrow = qw0 + qt * 16 + lc;
#pragma unroll
                    for (int kt = 0; kt < 4; ++kt)
#pragma unroll
                        for (int r = 0; r < 4; ++r) {
                            int kk = kvb + kt * 16 + lg * 4 + r;
                            pe[kt][r] = (kk > qrow) ? 0.f : exp2_fast(st[kt][r]);
                        }
                } else {
#pragma unroll
                    for (int kt = 0; kt < 4; ++kt)
#pragma unroll
                        for (int r = 0; r < 4; ++r) pe[kt][r] = exp2_fast(st[kt][r]);
                }

                // pack P (truncate) into 8 u32 words
                unsigned Wk[4][2];
#pragma unroll
                for (int kt = 0; kt < 4; ++kt) {
                    Wk[kt][0] = __builtin_amdgcn_perm(__float_as_uint(pe[kt][1]), __float_as_uint(pe[kt][0]), 0x07060302u);
                    Wk[kt][1] = __builtin_amdgcn_perm(__float_as_uint(pe[kt][3]), __float_as_uint(pe[kt][2]), 0x07060302u);
                }
                // in-register transpose: per (c,h): swap32 then swap16
                unsigned T0[4], T1[4];
#pragma unroll
                for (int hh = 0; hh < 2; ++hh) {
                    unsigned a0 = Wk[0][hh], b0 = Wk[1][hh];
                    permswap32(a0, b0);
                    permswap16(a0, b0);
                    T0[hh] = a0; T0[2 + hh] = b0;
                    unsigned a1 = Wk[2][hh], b1 = Wk[3][hh];
                    permswap32(a1, b1);
                    permswap16(a1, b1);
                    T1[hh] = a1; T1[2 + hh] = b1;
                }
                union { u32x4 u; bf16x8 v; } cv0, cv1;
                cv0.u = (u32x4){T0[0], T0[1], T0[2], T0[3]};
                cv1.u = (u32x4){T1[0], T1[1], T1[2], T1[3]};
                pf[qt][0] = cv0.v;
                pf[qt][1] = cv1.v;
            }

            // ---- O^T += V^T P^T (16 MFMA) and l += 1^T P^T (4 MFMA) ----
            __builtin_amdgcn_s_setprio(1);
#pragma unroll
            for (int qt = 0; qt < 2; ++qt) {
                lacc[qt] = MFMA16(ones, pf[qt][0], lacc[qt]);
                lacc[qt] = MFMA16(ones, pf[qt][1], lacc[qt]);
            }
#pragma unroll
            for (int dt = 0; dt < 4; ++dt)
#pragma unroll
                for (int c = 0; c < 2; ++c) {
                    bf16x8 vtf = *(const bf16x8*)&VTs[cur][dt * 16 + lc][((4 * c + lg) ^ lc7) * 8];
#pragma unroll
                    for (int qt = 0; qt < 2; ++qt)
                        oacc[qt][dt] = MFMA16(vtf, pf[qt][c], oacc[qt][dt]);
                }
            __builtin_amdgcn_s_setprio(0);
        }

        // write next tile into the other buffer (nobody reads it until next barrier)
        if (havenext) {
            *(bf16x8*)&Ks[cur ^ 1][r0][swz]       = nk0;
            *(bf16x8*)&Ks[cur ^ 1][r0 + 32][swz]  = nk1;
            *(bf16x8*)&VTs[cur ^ 1][r0][swz]      = nv0;
            *(bf16x8*)&VTs[cur ^ 1][r0 + 32][swz] = nv1;
        }
        cur ^= 1;
    }

    // epilogue: normalize (l already per-lane via ones-MFMA), add residual, vec4 store
#pragma unroll
    for (int qt = 0; qt < 2; ++qt) {
        float li = 1.0f / lacc[qt][0];
        const int q = qw0 + qt * 16 + lc;
        const size_t obase = ((size_t)b * 2048 + q) * 1024 + (size_t)h * 64 + lg * 4;
#pragma unroll
        for (int dt = 0; dt < 4; ++dt) {
            const size_t oi = obase + dt * 16;
            float4 xv = *(const float4*)(x + oi);
            float4 ov;
            ov.x = xv.x + oacc[qt][dt][0] * li;
            ov.y = xv.y + oacc[qt][dt][1] * li;
            ov.z = xv.z + oacc[qt][dt][2] * li;
            ov.w = xv.w + oacc[qt][dt][3] * li;
            *(float4*)(outp + oi) = ov;
        }
    }
}

extern "C" void kernel_launch(void* const* d_in, const int* in_sizes, int n_in,
                              void* d_out, int out_size, void* d_ws, size_t ws_size,
                              hipStream_t stream) {
    const float* x  = (const float*)d_in[0];
    const float* k  = (const float*)d_in[1];
    const float* v  = (const float*)d_in[2];
    const float* wq = (const float*)d_in[3];
    float* outp = (float*)d_out;

    const size_t NELEM = (size_t)4 * 2048 * 1024;
    unsigned short* qbuf = (unsigned short*)d_ws;
    unsigned short* kbuf = qbuf + NELEM;
    unsigned short* vtbuf = kbuf + NELEM;

    qproj_kernel<<<dim3(64, 8), 256, 0, stream>>>(x, wq, qbuf);
    convtrans_kernel<<<8192 + 2048, 256, 0, stream>>>(k, v, kbuf, vtbuf);
    attn_kernel<<<dim3(64, 16), 256, 0, stream>>>(qbuf, kbuf, vtbuf, x, outp);
}

// Round 15
// 97.736 us; speedup vs baseline: 1.1451x; 1.1412x over previous
//
#include <hip/hip_runtime.h>
#include <hip/hip_bf16.h>

// B=4, S=2048, D=1024, H=16, DH=64
typedef __attribute__((ext_vector_type(4))) float f32x4;
typedef __attribute__((ext_vector_type(8))) short bf16x8;
typedef __attribute__((ext_vector_type(4))) unsigned short u16x4;

#define MFMA16(a, b, c) __builtin_amdgcn_mfma_f32_16x16x32_bf16((a), (b), (c), 0, 0, 0)

static __device__ __forceinline__ unsigned short f2bf(float f) {
    unsigned u = __float_as_uint(f);
    u += 0x7FFFu + ((u >> 16) & 1u);   // RNE
    return (unsigned short)(u >> 16);
}
// pack 4 floats -> 4 bf16 (round-half-up) as uint2, via v_perm_b32
static __device__ __forceinline__ uint2 pack4_rhu(float4 v) {
    unsigned a = __float_as_uint(v.x) + 0x8000u;
    unsigned b = __float_as_uint(v.y) + 0x8000u;
    unsigned c = __float_as_uint(v.z) + 0x8000u;
    unsigned d = __float_as_uint(v.w) + 0x8000u;
    uint2 r;
    r.x = __builtin_amdgcn_perm(b, a, 0x07060302u);
    r.y = __builtin_amdgcn_perm(d, c, 0x07060302u);
    return r;
}
static __device__ __forceinline__ float exp2_fast(float x) {
#if __has_builtin(__builtin_amdgcn_exp2f)
    return __builtin_amdgcn_exp2f(x);
#else
    return exp2f(x);
#endif
}

// scores premultiplied so softmax runs in exp2 domain: c = log2(e)/32
#define QSCALE 0.04508422002778011f

// ---------------- merged prep: qproj (blocks 0..511) + k-conv (512..8703)
// ---------------- + v-trans (8704..10751). Memory-bound conv blocks backfill
// ---------------- around MFMA-bound qproj blocks in one co-scheduled launch.
__global__ __launch_bounds__(256) void prep_kernel(const float* __restrict__ x,
                                                   const float* __restrict__ wq,
                                                   const float* __restrict__ kin,
                                                   const float* __restrict__ vin,
                                                   unsigned short* __restrict__ qout,
                                                   unsigned short* __restrict__ kb,
                                                   unsigned short* __restrict__ vt) {
    __shared__ __align__(16) unsigned short As[2][128][40];   // 20KB (reused by v-trans)
    __shared__ __align__(16) unsigned short Bs[2][128][40];   // 20KB
    const int bid = blockIdx.x;
    const int tid = threadIdx.x;

    if (bid < 512) {
        // ---------------- Q projection: q = (x @ Wq^T) * QSCALE, bf16 [B,H,S,DH] ----------------
        const int m0 = (bid & 63) * 128;
        const int n0 = (bid >> 6) * 128;
        const int wave = tid >> 6, lane = tid & 63;
        const int lg = lane >> 4, lc = lane & 15;
        const int wm = wave >> 1, wn = wave & 1;

        f32x4 acc[4][4];
#pragma unroll
        for (int i = 0; i < 4; ++i)
#pragma unroll
            for (int j = 0; j < 4; ++j) acc[i][j] = (f32x4){0.f, 0.f, 0.f, 0.f};

        float4 ax[4], bx[4];
#pragma unroll
        for (int i = 0; i < 4; ++i) {
            int c = tid + i * 256;
            int row = c >> 3, kc = (c & 7) * 4;
            ax[i] = *(const float4*)(x  + (size_t)(m0 + row) * 1024 + kc);
            bx[i] = *(const float4*)(wq + (size_t)(n0 + row) * 1024 + kc);
        }
#pragma unroll
        for (int i = 0; i < 4; ++i) {
            int c = tid + i * 256;
            int row = c >> 3, kc = (c & 7) * 4;
            *(uint2*)&As[0][row][kc] = pack4_rhu(ax[i]);
            *(uint2*)&Bs[0][row][kc] = pack4_rhu(bx[i]);
        }

        int cur = 0;
        for (int ki = 0; ki < 32; ++ki) {
            __syncthreads();
            const bool havenext = (ki + 1 < 32);
            if (havenext) {
                int ks = (ki + 1) * 32;
#pragma unroll
                for (int i = 0; i < 4; ++i) {
                    int c = tid + i * 256;
                    int row = c >> 3, kc = (c & 7) * 4;
                    ax[i] = *(const float4*)(x  + (size_t)(m0 + row) * 1024 + ks + kc);
                    bx[i] = *(const float4*)(wq + (size_t)(n0 + row) * 1024 + ks + kc);
                }
            }
            bf16x8 af[4], bfr[4];
#pragma unroll
            for (int i = 0; i < 4; ++i) {
                af[i]  = *(const bf16x8*)&As[cur][wm * 64 + i * 16 + lc][lg * 8];
                bfr[i] = *(const bf16x8*)&Bs[cur][wn * 64 + i * 16 + lc][lg * 8];
            }
            __builtin_amdgcn_s_setprio(1);
#pragma unroll
            for (int mi = 0; mi < 4; ++mi)
#pragma unroll
                for (int ni = 0; ni < 4; ++ni)
                    acc[mi][ni] = MFMA16(af[mi], bfr[ni], acc[mi][ni]);
            __builtin_amdgcn_s_setprio(0);
            if (havenext) {
#pragma unroll
                for (int i = 0; i < 4; ++i) {
                    int c = tid + i * 256;
                    int row = c >> 3, kc = (c & 7) * 4;
                    *(uint2*)&As[cur ^ 1][row][kc] = pack4_rhu(ax[i]);
                    *(uint2*)&Bs[cur ^ 1][row][kc] = pack4_rhu(bx[i]);
                }
            }
            cur ^= 1;
        }
#pragma unroll
        for (int mi = 0; mi < 4; ++mi)
#pragma unroll
            for (int ni = 0; ni < 4; ++ni)
#pragma unroll
                for (int r = 0; r < 4; ++r) {
                    int m = m0 + wm * 64 + mi * 16 + lg * 4 + r;
                    int n = n0 + wn * 64 + ni * 16 + lc;
                    int b = m >> 11, s = m & 2047;
                    int h = n >> 6, dh = n & 63;
                    qout[(((size_t)b * 16 + h) * 2048 + s) * 64 + dh] = f2bf(acc[mi][ni][r] * QSCALE);
                }
    } else if (bid < 512 + 8192) {
        // ---------------- k fp32 -> bf16 ----------------
        int i = (bid - 512) * 256 + tid;
        float4 v = ((const float4*)kin)[i];
        u16x4 o = { f2bf(v.x), f2bf(v.y), f2bf(v.z), f2bf(v.w) };
        ((u16x4*)kb)[i] = o;
    } else {
        // ---------------- v fp32 [B,H,S,DH] -> bf16 [B,H,DH,S] ----------------
        float (*buf)[65] = (float (*)[65])(&As[0][0][0]);   // 16.6KB, fits in As
        const int idx = bid - (512 + 8192);
        const int s0 = (idx & 31) * 64;
        const int bh = idx >> 5;
#pragma unroll
        for (int i = 0; i < 4; ++i) {
            int c = tid + i * 256;
            int s = c >> 4, dc = (c & 15) * 4;
            float4 val = *(const float4*)(vin + ((size_t)bh * 2048 + s0 + s) * 64 + dc);
            buf[s][dc] = val.x; buf[s][dc + 1] = val.y; buf[s][dc + 2] = val.z; buf[s][dc + 3] = val.w;
        }
        __syncthreads();
#pragma unroll
        for (int i = 0; i < 4; ++i) {
            int c = tid + i * 256;
            int dh = c >> 4, sc = (c & 15) * 4;
            u16x4 o = { f2bf(buf[sc][dh]), f2bf(buf[sc + 1][dh]), f2bf(buf[sc + 2][dh]), f2bf(buf[sc + 3][dh]) };
            *(u16x4*)(vt + ((size_t)bh * 64 + dh) * 2048 + s0 + sc) = o;
        }
    }
}

// ---------------- fused causal flash attention + residual (R10 body, best measured) ----------------
// grid: (64 bh, 16), qb = 15 - blockIdx.y -> LPT dispatch (longest first, x fastest).
// 256 threads (4 waves) x 32 q-rows = one 128-row q-block per block.
// LDS 50KB (double-buffered K/VT + Ps) -> 3 blocks/CU: 768 slots < 1024 blocks
// = real backfill queue holding the shortest blocks.
// One barrier/iter: issue loads(next) after barrier, compute(cur), ds_write(next).
// Swapped QK^T & PV; no-max exp2 softmax; deferred l-reduction; vec4 epilogue.
__global__ __launch_bounds__(256, 3) void attn_kernel(const unsigned short* __restrict__ qg,
                                                      const unsigned short* __restrict__ kg,
                                                      const unsigned short* __restrict__ vtg,
                                                      const float* __restrict__ x,
                                                      float* __restrict__ outp) {
    __shared__ __align__(16) unsigned short Ks[2][64][64];
    __shared__ __align__(16) unsigned short VTs[2][64][64];
    __shared__ __align__(16) unsigned short Ps[4][32][72];

    const int bh = blockIdx.x;
    const int qb = 15 - blockIdx.y;
    const int b = bh >> 4, h = bh & 15;
    const int tid = threadIdx.x;
    const int wave = tid >> 6, lane = tid & 63;
    const int lg = lane >> 4, lc = lane & 15;
    const int lc7 = lc & 7;
    const int qw0 = qb * 128 + wave * 32;
    const int nkv = 2 * qb + 2;

    // staging: 256 threads cover 512 chunks of K and VT (2 rows each, same c16)
    const int r0  = tid >> 3;            // 0..31
    const int c16 = tid & 7;
    const int swz = (c16 ^ (r0 & 7)) * 8;    // same for r0+32 (low 3 bits equal)
    const unsigned short* kbase = kg  + ((size_t)bh * 2048 + r0) * 64 + c16 * 8;
    const unsigned short* vbase = vtg + ((size_t)bh * 64 + r0) * 2048 + c16 * 8;

    // Q B-frags in registers: qf[qt][c] = Q[qw0+qt*16+lc][c*32 + lg*8 ..]
    bf16x8 qf[2][2];
#pragma unroll
    for (int qt = 0; qt < 2; ++qt)
#pragma unroll
        for (int c = 0; c < 2; ++c)
            qf[qt][c] = *(const bf16x8*)(qg + ((size_t)bh * 2048 + qw0 + qt * 16 + lc) * 64 + c * 32 + lg * 8);

    f32x4 oacc[2][4];   // O^T: col=lc=q-local, row=lg*4+r=dh-local
#pragma unroll
    for (int qt = 0; qt < 2; ++qt)
#pragma unroll
        for (int dt = 0; dt < 4; ++dt) oacc[qt][dt] = (f32x4){0.f, 0.f, 0.f, 0.f};
    float l_r[2] = {0.f, 0.f};   // lane-local partials; cross-group reduce in epilogue

    {   // prologue: stage tile 0 into buffer 0
        *(bf16x8*)&Ks[0][r0][swz]       = *(const bf16x8*)(kbase);
        *(bf16x8*)&Ks[0][r0 + 32][swz]  = *(const bf16x8*)(kbase + 2048);
        *(bf16x8*)&VTs[0][r0][swz]      = *(const bf16x8*)(vbase);
        *(bf16x8*)&VTs[0][r0 + 32][swz] = *(const bf16x8*)(vbase + 65536);
    }

    int cur = 0;
    for (int kv = 0; kv < nkv; ++kv) {
        __syncthreads();   // buf[cur] staged & visible; buf[cur^1] readers done

        const bool havenext = (kv + 1 < nkv);
        const int nxt = havenext ? kv + 1 : kv;
        bf16x8 nk0 = *(const bf16x8*)(kbase + (size_t)nxt * 4096);
        bf16x8 nk1 = *(const bf16x8*)(kbase + (size_t)nxt * 4096 + 2048);
        bf16x8 nv0 = *(const bf16x8*)(vbase + nxt * 64);
        bf16x8 nv1 = *(const bf16x8*)(vbase + nxt * 64 + 65536);

        const bool active = (kv * 64 <= qw0 + 31);
        if (active) {
            // K A-frags (shared across both q-tiles)
            bf16x8 kf[4][2];
#pragma unroll
            for (int kt = 0; kt < 4; ++kt)
#pragma unroll
                for (int c = 0; c < 2; ++c)
                    kf[kt][c] = *(const bf16x8*)&Ks[cur][kt * 16 + lc][((4 * c + lg) ^ lc7) * 8];

            const int kvb = kv * 64;
            // ---- per q-tile: S^T = K Q^T (8 MFMA), softmax, pack -> Ps ----
#pragma unroll
            for (int qt = 0; qt < 2; ++qt) {
                f32x4 st[4];
                __builtin_amdgcn_s_setprio(1);
#pragma unroll
                for (int kt = 0; kt < 4; ++kt) {
                    f32x4 a = (f32x4){0.f, 0.f, 0.f, 0.f};
                    a = MFMA16(kf[kt][0], qf[qt][0], a);
                    a = MFMA16(kf[kt][1], qf[qt][1], a);
                    st[kt] = a;
                }
                __builtin_amdgcn_s_setprio(0);

                float pp[4][4];
#pragma unroll
                for (int kt = 0; kt < 4; ++kt)
#pragma unroll
                    for (int r = 0; r < 4; ++r) pp[kt][r] = st[kt][r];
                if (kvb + 63 > qw0 + qt * 16) {   // diagonal tile only
                    const int qrow = qw0 + qt * 16 + lc;
#pragma unroll
                    for (int kt = 0; kt < 4; ++kt)
#pragma unroll
                        for (int r = 0; r < 4; ++r) {
                            int kk = kvb + kt * 16 + lg * 4 + r;
                            if (kk > qrow) pp[kt][r] = -1e30f;
                        }
                }
                float rs = 0.f;
#pragma unroll
                for (int kt = 0; kt < 4; ++kt)
#pragma unroll
                    for (int r = 0; r < 4; ++r) {
                        float e = exp2_fast(pp[kt][r]);
                        pp[kt][r] = e;
                        rs += e;
                    }
                l_r[qt] += rs;
#pragma unroll
                for (int kt = 0; kt < 4; ++kt) {
                    uint2 w;
                    w.x = __builtin_amdgcn_perm(__float_as_uint(pp[kt][1]), __float_as_uint(pp[kt][0]), 0x07060302u);
                    w.y = __builtin_amdgcn_perm(__float_as_uint(pp[kt][3]), __float_as_uint(pp[kt][2]), 0x07060302u);
                    *(uint2*)&Ps[wave][qt * 16 + lc][kt * 16 + lg * 4] = w;
                }
            }
            asm volatile("s_waitcnt lgkmcnt(0)" ::: "memory");

            // ---- O^T += V^T P^T : 16 MFMA, vtf shared across q-tiles ----
            bf16x8 pf[2][2];
#pragma unroll
            for (int qt = 0; qt < 2; ++qt)
#pragma unroll
                for (int c = 0; c < 2; ++c)
                    pf[qt][c] = *(const bf16x8*)&Ps[wave][qt * 16 + lc][c * 32 + lg * 8];
            __builtin_amdgcn_s_setprio(1);
#pragma unroll
            for (int dt = 0; dt < 4; ++dt)
#pragma unroll
                for (int c = 0; c < 2; ++c) {
                    bf16x8 vtf = *(const bf16x8*)&VTs[cur][dt * 16 + lc][((4 * c + lg) ^ lc7) * 8];
#pragma unroll
                    for (int qt = 0; qt < 2; ++qt)
                        oacc[qt][dt] = MFMA16(vtf, pf[qt][c], oacc[qt][dt]);
                }
            __builtin_amdgcn_s_setprio(0);
        }

        // write next tile into the other buffer (nobody reads it until next barrier)
        if (havenext) {
            *(bf16x8*)&Ks[cur ^ 1][r0][swz]       = nk0;
            *(bf16x8*)&Ks[cur ^ 1][r0 + 32][swz]  = nk1;
            *(bf16x8*)&VTs[cur ^ 1][r0][swz]      = nv0;
            *(bf16x8*)&VTs[cur ^ 1][r0 + 32][swz] = nv1;
        }
        cur ^= 1;
    }

    // epilogue: finish l reduction, normalize, add residual, vec4 store
#pragma unroll
    for (int qt = 0; qt < 2; ++qt) {
        float lt = l_r[qt];
        lt += __shfl_xor(lt, 16, 64);
        lt += __shfl_xor(lt, 32, 64);
        float li = 1.0f / lt;
        const int q = qw0 + qt * 16 + lc;
        const size_t obase = ((size_t)b * 2048 + q) * 1024 + (size_t)h * 64 + lg * 4;
#pragma unroll
        for (int dt = 0; dt < 4; ++dt) {
            const size_t oi = obase + dt * 16;
            float4 xv = *(const float4*)(x + oi);
            float4 ov;
            ov.x = xv.x + oacc[qt][dt][0] * li;
            ov.y = xv.y + oacc[qt][dt][1] * li;
            ov.z = xv.z + oacc[qt][dt][2] * li;
            ov.w = xv.w + oacc[qt][dt][3] * li;
            *(float4*)(outp + oi) = ov;
        }
    }
}

extern "C" void kernel_launch(void* const* d_in, const int* in_sizes, int n_in,
                              void* d_out, int out_size, void* d_ws, size_t ws_size,
                              hipStream_t stream) {
    const float* x  = (const float*)d_in[0];
    const float* k  = (const float*)d_in[1];
    const float* v  = (const float*)d_in[2];
    const float* wq = (const float*)d_in[3];
    float* outp = (float*)d_out;

    const size_t NELEM = (size_t)4 * 2048 * 1024;
    unsigned short* qbuf = (unsigned short*)d_ws;
    unsigned short* kbuf = qbuf + NELEM;
    unsigned short* vtbuf = kbuf + NELEM;

    // merged prep: 512 qproj blocks + 8192 k-conv blocks + 2048 v-trans blocks
    prep_kernel<<<512 + 8192 + 2048, 256, 0, stream>>>(x, wq, k, v, qbuf, kbuf, vtbuf);
    attn_kernel<<<dim3(64, 16), 256, 0, stream>>>(qbuf, kbuf, vtbuf, x, outp);
}

// Round 16
// 96.859 us; speedup vs baseline: 1.1554x; 1.0091x over previous
//
#include <hip/hip_runtime.h>
#include <hip/hip_bf16.h>

// B=4, S=2048, D=1024, H=16, DH=64
typedef __attribute__((ext_vector_type(4))) float f32x4;
typedef __attribute__((ext_vector_type(8))) short bf16x8;
typedef __attribute__((ext_vector_type(4))) unsigned short u16x4;

#define MFMA16(a, b, c) __builtin_amdgcn_mfma_f32_16x16x32_bf16((a), (b), (c), 0, 0, 0)

static __device__ __forceinline__ unsigned short f2bf(float f) {
    unsigned u = __float_as_uint(f);
    u += 0x7FFFu + ((u >> 16) & 1u);   // RNE
    return (unsigned short)(u >> 16);
}
// pack 4 floats -> 4 bf16 (round-half-up) as uint2, via v_perm_b32
static __device__ __forceinline__ uint2 pack4_rhu(float4 v) {
    unsigned a = __float_as_uint(v.x) + 0x8000u;
    unsigned b = __float_as_uint(v.y) + 0x8000u;
    unsigned c = __float_as_uint(v.z) + 0x8000u;
    unsigned d = __float_as_uint(v.w) + 0x8000u;
    uint2 r;
    r.x = __builtin_amdgcn_perm(b, a, 0x07060302u);
    r.y = __builtin_amdgcn_perm(d, c, 0x07060302u);
    return r;
}
static __device__ __forceinline__ float exp2_fast(float x) {
#if __has_builtin(__builtin_amdgcn_exp2f)
    return __builtin_amdgcn_exp2f(x);
#else
    return exp2f(x);
#endif
}

// scores premultiplied so softmax runs in exp2 domain: c = log2(e)/32
#define QSCALE 0.04508422002778011f

// ---------------- merged prep: qproj (blocks 0..511) + k-conv (512..2559, 4x work)
// ---------------- + v-trans (2560..4607). Conv blocks carry 4 independent loads
// ---------------- each (64B in flight/thread) so 4 blocks/CU sustains HBM BW.
__global__ __launch_bounds__(256) void prep_kernel(const float* __restrict__ x,
                                                   const float* __restrict__ wq,
                                                   const float* __restrict__ kin,
                                                   const float* __restrict__ vin,
                                                   unsigned short* __restrict__ qout,
                                                   unsigned short* __restrict__ kb,
                                                   unsigned short* __restrict__ vt) {
    __shared__ __align__(16) unsigned short As[2][128][40];   // 20KB (reused by v-trans)
    __shared__ __align__(16) unsigned short Bs[2][128][40];   // 20KB
    const int bid = blockIdx.x;
    const int tid = threadIdx.x;

    if (bid < 512) {
        // ---------------- Q projection: q = (x @ Wq^T) * QSCALE, bf16 [B,H,S,DH] ----------------
        const int m0 = (bid & 63) * 128;
        const int n0 = (bid >> 6) * 128;
        const int wave = tid >> 6, lane = tid & 63;
        const int lg = lane >> 4, lc = lane & 15;
        const int wm = wave >> 1, wn = wave & 1;

        f32x4 acc[4][4];
#pragma unroll
        for (int i = 0; i < 4; ++i)
#pragma unroll
            for (int j = 0; j < 4; ++j) acc[i][j] = (f32x4){0.f, 0.f, 0.f, 0.f};

        float4 ax[4], bx[4];
#pragma unroll
        for (int i = 0; i < 4; ++i) {
            int c = tid + i * 256;
            int row = c >> 3, kc = (c & 7) * 4;
            ax[i] = *(const float4*)(x  + (size_t)(m0 + row) * 1024 + kc);
            bx[i] = *(const float4*)(wq + (size_t)(n0 + row) * 1024 + kc);
        }
#pragma unroll
        for (int i = 0; i < 4; ++i) {
            int c = tid + i * 256;
            int row = c >> 3, kc = (c & 7) * 4;
            *(uint2*)&As[0][row][kc] = pack4_rhu(ax[i]);
            *(uint2*)&Bs[0][row][kc] = pack4_rhu(bx[i]);
        }

        int cur = 0;
        for (int ki = 0; ki < 32; ++ki) {
            __syncthreads();
            const bool havenext = (ki + 1 < 32);
            if (havenext) {
                int ks = (ki + 1) * 32;
#pragma unroll
                for (int i = 0; i < 4; ++i) {
                    int c = tid + i * 256;
                    int row = c >> 3, kc = (c & 7) * 4;
                    ax[i] = *(const float4*)(x  + (size_t)(m0 + row) * 1024 + ks + kc);
                    bx[i] = *(const float4*)(wq + (size_t)(n0 + row) * 1024 + ks + kc);
                }
            }
            bf16x8 af[4], bfr[4];
#pragma unroll
            for (int i = 0; i < 4; ++i) {
                af[i]  = *(const bf16x8*)&As[cur][wm * 64 + i * 16 + lc][lg * 8];
                bfr[i] = *(const bf16x8*)&Bs[cur][wn * 64 + i * 16 + lc][lg * 8];
            }
            __builtin_amdgcn_s_setprio(1);
#pragma unroll
            for (int mi = 0; mi < 4; ++mi)
#pragma unroll
                for (int ni = 0; ni < 4; ++ni)
                    acc[mi][ni] = MFMA16(af[mi], bfr[ni], acc[mi][ni]);
            __builtin_amdgcn_s_setprio(0);
            if (havenext) {
#pragma unroll
                for (int i = 0; i < 4; ++i) {
                    int c = tid + i * 256;
                    int row = c >> 3, kc = (c & 7) * 4;
                    *(uint2*)&As[cur ^ 1][row][kc] = pack4_rhu(ax[i]);
                    *(uint2*)&Bs[cur ^ 1][row][kc] = pack4_rhu(bx[i]);
                }
            }
            cur ^= 1;
        }
#pragma unroll
        for (int mi = 0; mi < 4; ++mi)
#pragma unroll
            for (int ni = 0; ni < 4; ++ni)
#pragma unroll
                for (int r = 0; r < 4; ++r) {
                    int m = m0 + wm * 64 + mi * 16 + lg * 4 + r;
                    int n = n0 + wn * 64 + ni * 16 + lc;
                    int b = m >> 11, s = m & 2047;
                    int h = n >> 6, dh = n & 63;
                    qout[(((size_t)b * 16 + h) * 2048 + s) * 64 + dh] = f2bf(acc[mi][ni][r] * QSCALE);
                }
    } else if (bid < 512 + 2048) {
        // ---------------- k fp32 -> bf16 : 4 independent strided chunks ----------------
        const int base = (bid - 512) * 256 + tid;     // 0..524287
        float4 v0 = ((const float4*)kin)[base];
        float4 v1 = ((const float4*)kin)[base + 524288];
        float4 v2 = ((const float4*)kin)[base + 1048576];
        float4 v3 = ((const float4*)kin)[base + 1572864];
        *(uint2*)&((u16x4*)kb)[base]           = pack4_rhu(v0);
        *(uint2*)&((u16x4*)kb)[base + 524288]  = pack4_rhu(v1);
        *(uint2*)&((u16x4*)kb)[base + 1048576] = pack4_rhu(v2);
        *(uint2*)&((u16x4*)kb)[base + 1572864] = pack4_rhu(v3);
    } else {
        // ---------------- v fp32 [B,H,S,DH] -> bf16 [B,H,DH,S] ----------------
        float (*buf)[65] = (float (*)[65])(&As[0][0][0]);   // 16.6KB, fits in As
        const int idx = bid - (512 + 2048);
        const int s0 = (idx & 31) * 64;
        const int bh = idx >> 5;
#pragma unroll
        for (int i = 0; i < 4; ++i) {
            int c = tid + i * 256;
            int s = c >> 4, dc = (c & 15) * 4;
            float4 val = *(const float4*)(vin + ((size_t)bh * 2048 + s0 + s) * 64 + dc);
            buf[s][dc] = val.x; buf[s][dc + 1] = val.y; buf[s][dc + 2] = val.z; buf[s][dc + 3] = val.w;
        }
        __syncthreads();
#pragma unroll
        for (int i = 0; i < 4; ++i) {
            int c = tid + i * 256;
            int dh = c >> 4, sc = (c & 15) * 4;
            u16x4 o = { f2bf(buf[sc][dh]), f2bf(buf[sc + 1][dh]), f2bf(buf[sc + 2][dh]), f2bf(buf[sc + 3][dh]) };
            *(u16x4*)(vt + ((size_t)bh * 64 + dh) * 2048 + s0 + sc) = o;
        }
    }
}

// ---------------- fused causal flash attention + residual (R10 body, best measured) ----------------
// grid: (64 bh, 16), qb = 15 - blockIdx.y -> LPT dispatch (longest first, x fastest).
// 256 threads (4 waves) x 32 q-rows = one 128-row q-block per block.
// LDS 50KB (double-buffered K/VT + Ps) -> 3 blocks/CU: 768 slots < 1024 blocks
// = real backfill queue holding the shortest blocks.
// One barrier/iter: issue loads(next) after barrier, compute(cur), ds_write(next).
// Swapped QK^T & PV; no-max exp2 softmax; deferred l-reduction; vec4 epilogue.
__global__ __launch_bounds__(256, 3) void attn_kernel(const unsigned short* __restrict__ qg,
                                                      const unsigned short* __restrict__ kg,
                                                      const unsigned short* __restrict__ vtg,
                                                      const float* __restrict__ x,
                                                      float* __restrict__ outp) {
    __shared__ __align__(16) unsigned short Ks[2][64][64];
    __shared__ __align__(16) unsigned short VTs[2][64][64];
    __shared__ __align__(16) unsigned short Ps[4][32][72];

    const int bh = blockIdx.x;
    const int qb = 15 - blockIdx.y;
    const int b = bh >> 4, h = bh & 15;
    const int tid = threadIdx.x;
    const int wave = tid >> 6, lane = tid & 63;
    const int lg = lane >> 4, lc = lane & 15;
    const int lc7 = lc & 7;
    const int qw0 = qb * 128 + wave * 32;
    const int nkv = 2 * qb + 2;

    // staging: 256 threads cover 512 chunks of K and VT (2 rows each, same c16)
    const int r0  = tid >> 3;            // 0..31
    const int c16 = tid & 7;
    const int swz = (c16 ^ (r0 & 7)) * 8;    // same for r0+32 (low 3 bits equal)
    const unsigned short* kbase = kg  + ((size_t)bh * 2048 + r0) * 64 + c16 * 8;
    const unsigned short* vbase = vtg + ((size_t)bh * 64 + r0) * 2048 + c16 * 8;

    // Q B-frags in registers: qf[qt][c] = Q[qw0+qt*16+lc][c*32 + lg*8 ..]
    bf16x8 qf[2][2];
#pragma unroll
    for (int qt = 0; qt < 2; ++qt)
#pragma unroll
        for (int c = 0; c < 2; ++c)
            qf[qt][c] = *(const bf16x8*)(qg + ((size_t)bh * 2048 + qw0 + qt * 16 + lc) * 64 + c * 32 + lg * 8);

    f32x4 oacc[2][4];   // O^T: col=lc=q-local, row=lg*4+r=dh-local
#pragma unroll
    for (int qt = 0; qt < 2; ++qt)
#pragma unroll
        for (int dt = 0; dt < 4; ++dt) oacc[qt][dt] = (f32x4){0.f, 0.f, 0.f, 0.f};
    float l_r[2] = {0.f, 0.f};   // lane-local partials; cross-group reduce in epilogue

    {   // prologue: stage tile 0 into buffer 0
        *(bf16x8*)&Ks[0][r0][swz]       = *(const bf16x8*)(kbase);
        *(bf16x8*)&Ks[0][r0 + 32][swz]  = *(const bf16x8*)(kbase + 2048);
        *(bf16x8*)&VTs[0][r0][swz]      = *(const bf16x8*)(vbase);
        *(bf16x8*)&VTs[0][r0 + 32][swz] = *(const bf16x8*)(vbase + 65536);
    }

    int cur = 0;
    for (int kv = 0; kv < nkv; ++kv) {
        __syncthreads();   // buf[cur] staged & visible; buf[cur^1] readers done

        const bool havenext = (kv + 1 < nkv);
        const int nxt = havenext ? kv + 1 : kv;
        bf16x8 nk0 = *(const bf16x8*)(kbase + (size_t)nxt * 4096);
        bf16x8 nk1 = *(const bf16x8*)(kbase + (size_t)nxt * 4096 + 2048);
        bf16x8 nv0 = *(const bf16x8*)(vbase + nxt * 64);
        bf16x8 nv1 = *(const bf16x8*)(vbase + nxt * 64 + 65536);

        const bool active = (kv * 64 <= qw0 + 31);
        if (active) {
            // K A-frags (shared across both q-tiles)
            bf16x8 kf[4][2];
#pragma unroll
            for (int kt = 0; kt < 4; ++kt)
#pragma unroll
                for (int c = 0; c < 2; ++c)
                    kf[kt][c] = *(const bf16x8*)&Ks[cur][kt * 16 + lc][((4 * c + lg) ^ lc7) * 8];

            const int kvb = kv * 64;
            // ---- per q-tile: S^T = K Q^T (8 MFMA), softmax, pack -> Ps ----
#pragma unroll
            for (int qt = 0; qt < 2; ++qt) {
                f32x4 st[4];
                __builtin_amdgcn_s_setprio(1);
#pragma unroll
                for (int kt = 0; kt < 4; ++kt) {
                    f32x4 a = (f32x4){0.f, 0.f, 0.f, 0.f};
                    a = MFMA16(kf[kt][0], qf[qt][0], a);
                    a = MFMA16(kf[kt][1], qf[qt][1], a);
                    st[kt] = a;
                }
                __builtin_amdgcn_s_setprio(0);

                float pp[4][4];
#pragma unroll
                for (int kt = 0; kt < 4; ++kt)
#pragma unroll
                    for (int r = 0; r < 4; ++r) pp[kt][r] = st[kt][r];
                if (kvb + 63 > qw0 + qt * 16) {   // diagonal tile only
                    const int qrow = qw0 + qt * 16 + lc;
#pragma unroll
                    for (int kt = 0; kt < 4; ++kt)
#pragma unroll
                        for (int r = 0; r < 4; ++r) {
                            int kk = kvb + kt * 16 + lg * 4 + r;
                            if (kk > qrow) pp[kt][r] = -1e30f;
                        }
                }
                float rs = 0.f;
#pragma unroll
                for (int kt = 0; kt < 4; ++kt)
#pragma unroll
                    for (int r = 0; r < 4; ++r) {
                        float e = exp2_fast(pp[kt][r]);
                        pp[kt][r] = e;
                        rs += e;
                    }
                l_r[qt] += rs;
#pragma unroll
                for (int kt = 0; kt < 4; ++kt) {
                    uint2 w;
                    w.x = __builtin_amdgcn_perm(__float_as_uint(pp[kt][1]), __float_as_uint(pp[kt][0]), 0x07060302u);
                    w.y = __builtin_amdgcn_perm(__float_as_uint(pp[kt][3]), __float_as_uint(pp[kt][2]), 0x07060302u);
                    *(uint2*)&Ps[wave][qt * 16 + lc][kt * 16 + lg * 4] = w;
                }
            }
            asm volatile("s_waitcnt lgkmcnt(0)" ::: "memory");

            // ---- O^T += V^T P^T : 16 MFMA, vtf shared across q-tiles ----
            bf16x8 pf[2][2];
#pragma unroll
            for (int qt = 0; qt < 2; ++qt)
#pragma unroll
                for (int c = 0; c < 2; ++c)
                    pf[qt][c] = *(const bf16x8*)&Ps[wave][qt * 16 + lc][c * 32 + lg * 8];
            __builtin_amdgcn_s_setprio(1);
#pragma unroll
            for (int dt = 0; dt < 4; ++dt)
#pragma unroll
                for (int c = 0; c < 2; ++c) {
                    bf16x8 vtf = *(const bf16x8*)&VTs[cur][dt * 16 + lc][((4 * c + lg) ^ lc7) * 8];
#pragma unroll
                    for (int qt = 0; qt < 2; ++qt)
                        oacc[qt][dt] = MFMA16(vtf, pf[qt][c], oacc[qt][dt]);
                }
            __builtin_amdgcn_s_setprio(0);
        }

        // write next tile into the other buffer (nobody reads it until next barrier)
        if (havenext) {
            *(bf16x8*)&Ks[cur ^ 1][r0][swz]       = nk0;
            *(bf16x8*)&Ks[cur ^ 1][r0 + 32][swz]  = nk1;
            *(bf16x8*)&VTs[cur ^ 1][r0][swz]      = nv0;
            *(bf16x8*)&VTs[cur ^ 1][r0 + 32][swz] = nv1;
        }
        cur ^= 1;
    }

    // epilogue: finish l reduction, normalize, add residual, vec4 store
#pragma unroll
    for (int qt = 0; qt < 2; ++qt) {
        float lt = l_r[qt];
        lt += __shfl_xor(lt, 16, 64);
        lt += __shfl_xor(lt, 32, 64);
        float li = 1.0f / lt;
        const int q = qw0 + qt * 16 + lc;
        const size_t obase = ((size_t)b * 2048 + q) * 1024 + (size_t)h * 64 + lg * 4;
#pragma unroll
        for (int dt = 0; dt < 4; ++dt) {
            const size_t oi = obase + dt * 16;
            float4 xv = *(const float4*)(x + oi);
            float4 ov;
            ov.x = xv.x + oacc[qt][dt][0] * li;
            ov.y = xv.y + oacc[qt][dt][1] * li;
            ov.z = xv.z + oacc[qt][dt][2] * li;
            ov.w = xv.w + oacc[qt][dt][3] * li;
            *(float4*)(outp + oi) = ov;
        }
    }
}

extern "C" void kernel_launch(void* const* d_in, const int* in_sizes, int n_in,
                              void* d_out, int out_size, void* d_ws, size_t ws_size,
                              hipStream_t stream) {
    const float* x  = (const float*)d_in[0];
    const float* k  = (const float*)d_in[1];
    const float* v  = (const float*)d_in[2];
    const float* wq = (const float*)d_in[3];
    float* outp = (float*)d_out;

    const size_t NELEM = (size_t)4 * 2048 * 1024;
    unsigned short* qbuf = (unsigned short*)d_ws;
    unsigned short* kbuf = qbuf + NELEM;
    unsigned short* vtbuf = kbuf + NELEM;

    // merged prep: 512 qproj + 2048 k-conv (4x work each) + 2048 v-trans
    prep_kernel<<<512 + 2048 + 2048, 256, 0, stream>>>(x, wq, k, v, qbuf, kbuf, vtbuf);
    attn_kernel<<<dim3(64, 16), 256, 0, stream>>>(qbuf, kbuf, vtbuf, x, outp);
}